// Round 3
// baseline (470.422 us; speedup 1.0000x reference)
//
#include <hip/hip_runtime.h>
#include <math.h>

#define N_NODES 8192
#define N_COMM 16
#define DIMS 64
#define ROWS 32                      // ricci rows per block (i-chunk)
#define JS 1024                      // j-strip per block: 256 thr x 4
#define NJB (N_NODES / JS)           // 8 j-strips
#define NIB (N_NODES / ROWS)         // 256 i-chunks -> grid 2048
#define DEPTH 4                      // ricci prefetch ring (rows in flight)
#define PITS (N_NODES + 64)          // piT row stride (padded: L2 channel spread)

typedef float v4f __attribute__((ext_vector_type(4)));

// ---------------------------------------------------------------------------
// Kernel 1: pi[i,k] = softmax_k( sqrt(d_euc^2 + d_lor^2 + d_sph^2) )
// One lane per (node, k): t = i*16 + k. 16-lane softmax via shfl_xor(1,2,4,8).
// Writes pi row-major AND transposed padded piT. Thread 0 zeroes accum+ctr.
// ---------------------------------------------------------------------------
__global__ __launch_bounds__(256) void k_pi(
    const float* __restrict__ node,   // (3, 8192, 64)
    const float* __restrict__ comm,   // (16, 64)
    float* __restrict__ pi,           // (8192, 16)
    float* __restrict__ piT,          // (16, PITS)
    double* __restrict__ accum,       // [0]=intra, [1]=inter
    unsigned* __restrict__ ctr)       // k_main finish counter
{
  const int t = blockIdx.x * blockDim.x + threadIdx.x;  // 0..131071
  if (t == 0) { accum[0] = 0.0; accum[1] = 0.0; *ctr = 0u; }
  const int i = t >> 4;
  const int k = t & 15;

  const float* xe = node + (size_t)i * DIMS;                  // Euclidean (curv 0)
  const float* xl = xe + (size_t)N_NODES * DIMS;              // Lorentz  (curv -1)
  const float* xs = xl + (size_t)N_NODES * DIMS;              // Sphere   (curv +1)
  const float* c  = comm + k * DIMS;

  float de = 0.f, il = 0.f, isp = 0.f;
#pragma unroll
  for (int d = 0; d < DIMS; d += 4) {
    v4f a  = *(const v4f*)(xe + d);
    v4f b  = *(const v4f*)(xl + d);
    v4f e  = *(const v4f*)(xs + d);
    v4f cv = *(const v4f*)(c + d);
    v4f df = a - cv;
    de  += df.x * df.x + df.y * df.y + df.z * df.z + df.w * df.w;
    il  += b.x * cv.x + b.y * cv.y + b.z * cv.z + b.w * cv.w;
    isp += e.x * cv.x + e.y * cv.y + e.z * cv.z + e.w * cv.w;
  }

  // Lorentz (kk = 1): lip = <x,c> - 2*x0*c0 ; d = arccosh(max(-lip, 1+eps))
  float lip = il - 2.0f * xl[0] * c[0];
  float arg = fmaxf(-lip, 1.0f + 1e-7f);
  float d1  = acoshf(arg);
  // Sphere: d = arccos(clip(<x,c>, -1+eps, 1-eps))
  float cs = fminf(fmaxf(isp, -1.0f + 1e-7f), 1.0f - 1e-7f);
  float d2 = acosf(cs);

  float dn = sqrtf(de + d1 * d1 + d2 * d2);

  // softmax over the 16 lanes sharing this node (lane mask bits 0..3)
  float m = dn;
#pragma unroll
  for (int off = 1; off < 16; off <<= 1) m = fmaxf(m, __shfl_xor(m, off));
  float ex = expf(dn - m);
  float ss = ex;
#pragma unroll
  for (int off = 1; off < 16; off <<= 1) ss += __shfl_xor(ss, off);

  float v = ex / ss;
  pi[t] = v;                     // coalesced
  piT[k * PITS + i] = v;         // scattered, tiny (one store/thread)
}

// ---------------------------------------------------------------------------
// Kernel 2: 2-D tiling, block = (32 rows) x (1024-j strip), thread = j-quad.
// R2 post-mortem fixes:
//   (a) pi rows for the i-chunk staged in LDS ONCE (2 KB) -- in-loop reads
//       are broadcast ds_read_b128, off the scalar path (R2: per-row s_load
//       bursts serialized on lgkmcnt inside the vmcnt shadow -> VALU 18%).
//   (b) ricci prefetch ring DEPTH=4 -- consume row ir waits vmcnt(3) on a
//       load issued 4 rows (~2700 wave-interleaved cycles) earlier. vmcnt
//       stream is PURE ricci (pi is LDS now), so counted waits stay clean.
// Per row: 1 coalesced dwordx4 + 4 broadcast ds_read_b128 + 84 VALU.
// ~115 VGPR -> 4 waves/SIMD. Epilogue: last block finalizes (fused k_final).
// ---------------------------------------------------------------------------
__global__ __launch_bounds__(256) void k_main(
    const float* __restrict__ ricci,   // (8192, 8192)
    const float* __restrict__ pi,      // (8192, 16) row-major
    const float* __restrict__ piT,     // (16, PITS)
    const float* __restrict__ alpha,   // scalar
    double* __restrict__ accum,        // [0]=intra_sum, [1]=inter_sum
    unsigned* __restrict__ ctr,
    float* __restrict__ out)
{
  const int tid = threadIdx.x;
  const int jb  = blockIdx.x & (NJB - 1);   // j-strip
  const int ib  = blockIdx.x >> 3;          // i-chunk (log2(NJB)=3)
  const int i0  = ib * ROWS;
  const int j   = jb * JS + tid * 4;

  // stage pi rows i0..i0+31 into LDS (512 floats, 2 coalesced loads)
  __shared__ float prs[ROWS * N_COMM];
  {
    const float* src = pi + (size_t)i0 * N_COMM;
    prs[tid]       = src[tid];
    prs[tid + 256] = src[tid + 256];
  }

  // one-time pi column fragments for this thread's j-quad (coalesced)
  v4f p[N_COMM];
#pragma unroll
  for (int k = 0; k < N_COMM; ++k)
    p[k] = *(const v4f*)(piT + (size_t)k * PITS + j);

  __syncthreads();

  const float* rptr = ricci + (size_t)i0 * N_NODES + j;

  // prologue: fill the ring (rows 0..DEPTH-1)
  v4f rv[DEPTH];
#pragma unroll
  for (int d = 0; d < DEPTH; ++d)
    rv[d] = *(const v4f*)(rptr + (size_t)d * N_NODES);

  float fi0 = 0.f, fi1 = 0.f, fi2 = 0.f, fi3 = 0.f;
  float finter = 0.f;

#pragma unroll
  for (int ir = 0; ir < ROWS; ++ir) {
    v4f r = rv[ir & (DEPTH - 1)];
    // prefetch row ir+DEPTH (issued before FMAs; newest in vmcnt order)
    if (ir + DEPTH < ROWS)
      rv[ir & (DEPTH - 1)] = *(const v4f*)(rptr + (size_t)(ir + DEPTH) * N_NODES);

    // broadcast LDS reads of this row's pi (4x ds_read_b128, same addr)
    const v4f* pr = (const v4f*)&prs[ir * N_COMM];
    v4f pa = pr[0], pb = pr[1], pc = pr[2], pd = pr[3];

    float s;
    s = r.x*p[ 0].x + r.y*p[ 0].y + r.z*p[ 0].z + r.w*p[ 0].w;  fi0 += pa.x * s;
    s = r.x*p[ 1].x + r.y*p[ 1].y + r.z*p[ 1].z + r.w*p[ 1].w;  fi1 += pa.y * s;
    s = r.x*p[ 2].x + r.y*p[ 2].y + r.z*p[ 2].z + r.w*p[ 2].w;  fi2 += pa.z * s;
    s = r.x*p[ 3].x + r.y*p[ 3].y + r.z*p[ 3].z + r.w*p[ 3].w;  fi3 += pa.w * s;
    s = r.x*p[ 4].x + r.y*p[ 4].y + r.z*p[ 4].z + r.w*p[ 4].w;  fi0 += pb.x * s;
    s = r.x*p[ 5].x + r.y*p[ 5].y + r.z*p[ 5].z + r.w*p[ 5].w;  fi1 += pb.y * s;
    s = r.x*p[ 6].x + r.y*p[ 6].y + r.z*p[ 6].z + r.w*p[ 6].w;  fi2 += pb.z * s;
    s = r.x*p[ 7].x + r.y*p[ 7].y + r.z*p[ 7].z + r.w*p[ 7].w;  fi3 += pb.w * s;
    s = r.x*p[ 8].x + r.y*p[ 8].y + r.z*p[ 8].z + r.w*p[ 8].w;  fi0 += pc.x * s;
    s = r.x*p[ 9].x + r.y*p[ 9].y + r.z*p[ 9].z + r.w*p[ 9].w;  fi1 += pc.y * s;
    s = r.x*p[10].x + r.y*p[10].y + r.z*p[10].z + r.w*p[10].w;  fi2 += pc.z * s;
    s = r.x*p[11].x + r.y*p[11].y + r.z*p[11].z + r.w*p[11].w;  fi3 += pc.w * s;
    s = r.x*p[12].x + r.y*p[12].y + r.z*p[12].z + r.w*p[12].w;  fi0 += pd.x * s;
    s = r.x*p[13].x + r.y*p[13].y + r.z*p[13].z + r.w*p[13].w;  fi1 += pd.y * s;
    s = r.x*p[14].x + r.y*p[14].y + r.z*p[14].z + r.w*p[14].w;  fi2 += pd.z * s;
    s = r.x*p[15].x + r.y*p[15].y + r.z*p[15].z + r.w*p[15].w;  fi3 += pd.w * s;

    finter += (r.x + r.y) + (r.z + r.w);
  }

  float fintra = (fi0 + fi1) + (fi2 + fi3);

  // wave reduce (64 lanes) in double, then block reduce, 2 atomics/block
  double di = (double)fintra, dn = (double)finter;
#pragma unroll
  for (int off = 32; off > 0; off >>= 1) {
    di += __shfl_down(di, off);
    dn += __shfl_down(dn, off);
  }
  __shared__ double red[8];
  const int w = tid >> 6;
  if ((tid & 63) == 0) { red[w] = di; red[4 + w] = dn; }
  __syncthreads();
  if (tid == 0) {
    atomicAdd(&accum[0], red[0] + red[1] + red[2] + red[3]);
    atomicAdd(&accum[1], red[4] + red[5] + red[6] + red[7]);
    // last-block finalize (fused k_final): device-scope atomics + fences
    __threadfence();
    unsigned prev = atomicAdd(ctr, 1u);
    if (prev == (unsigned)gridDim.x - 1u) {
      __threadfence();
      double ia = atomicAdd(&accum[0], 0.0);   // coherent device-scope read
      double ir2 = atomicAdd(&accum[1], 0.0);
      const double KN  = (double)N_COMM * (double)N_NODES;
      const double KKN = (double)N_COMM * (double)N_COMM * (double)N_NODES;
      out[0] = (float)((double)alpha[0] * (ia / KN) - ir2 / KKN);
    }
  }
}

extern "C" void kernel_launch(void* const* d_in, const int* in_sizes, int n_in,
                              void* d_out, int out_size, void* d_ws, size_t ws_size,
                              hipStream_t stream) {
  (void)in_sizes; (void)n_in; (void)out_size; (void)ws_size;

  const float* node  = (const float*)d_in[0];  // (3, 8192, 64) fp32
  const float* comm  = (const float*)d_in[1];  // (16, 64) fp32
  const float* ricci = (const float*)d_in[2];  // (8192, 8192) fp32
  const float* alpha = (const float*)d_in[3];  // scalar fp32
  float* out = (float*)d_out;

  double*   accum = (double*)d_ws;                         // 2 doubles @ 0
  unsigned* ctr   = (unsigned*)((char*)d_ws + 16);         // finish counter
  float*    pi    = (float*)((char*)d_ws + 64);            // 512 KB
  float*    piT   = (float*)((char*)d_ws + 64 + 524288);   // 16*PITS*4 = 528 KB

  // accum/ctr zeroed by k_pi thread 0 (in-stream, before k_main) -- no memset.
  hipLaunchKernelGGL(k_pi,   dim3((N_NODES * N_COMM) / 256), dim3(256), 0, stream,
                     node, comm, pi, piT, accum, ctr);
  hipLaunchKernelGGL(k_main, dim3(NIB * NJB), dim3(256), 0, stream,
                     ricci, pi, piT, alpha, accum, ctr, out);
}